// Round 1
// baseline (155.951 us; speedup 1.0000x reference)
//
#include <hip/hip_runtime.h>
#include <hip/hip_bf16.h>
#include <stdint.h>

typedef unsigned short ushort_t;

// ---------------------------------------------------------------------------
// Pre-kernel: convert W1d (1024x64 fp32) into bf16, transposed to
// Wt[g][k][o][j]  (g=group 0..7, k=c-block 0..7, o=0..127, j=c within block)
// so the fused kernel's conv1d loads are coalesced 16B per lane.
// ---------------------------------------------------------------------------
__global__ void __launch_bounds__(256) w1d_to_bf16(const float* __restrict__ W1d,
                                                   ushort_t* __restrict__ Wt) {
    int t = blockIdx.x * 256 + threadIdx.x;      // 0..8191
    int g = t >> 10, k = (t >> 7) & 7, o = t & 127;
    const float* src = W1d + (((g << 7) + o) << 6) + (k << 3);
    ushort_t* dst = Wt + ((((g << 3) + k) << 7) + o) * 8;
#pragma unroll
    for (int j = 0; j < 8; ++j) {
        uint32_t u = __float_as_uint(src[j]);
        uint32_t r = (u + 0x7FFFu + ((u >> 16) & 1u)) >> 16;   // RN to bf16
        dst[j] = (ushort_t)r;
    }
}

// ---------------------------------------------------------------------------
// Fused kernel: one block per (b,h).  x tile read once from HBM.
//   phase 1: stage x[b,h] (32x384 fp32) into padded LDS
//   phase 2: y[e][w] = x[w,:].W2d[e,:] + b2d   (split-K over 4 waves)
//   phase 3: z[g][o] = Wg[g,o,:].y[g,:] + b1d ; softmax over v -> attn in LDS
//   phase 4: out[u,:] = sum_v attn[u][v] * x[v,:]
// ---------------------------------------------------------------------------
template <bool WBF>
__global__ void __launch_bounds__(256, 2) dynamixer_fused(
    const float* __restrict__ x,
    const float* __restrict__ W2d,
    const float* __restrict__ b2d,
    const float* __restrict__ W1d,
    const float* __restrict__ b1d,
    const ushort_t* __restrict__ Wt,
    float* __restrict__ out)
{
    __shared__ float xs[32 * 388];   // rows padded to 97 float4 (388 floats)
    __shared__ float ys[512];        // y, flat index e*32+w == g*64+c
    __shared__ float zs[32 * 32];    // attn[u][v]
    __shared__ float red[4 * 512];   // split-K partials

    const int t = threadIdx.x;
    const int blk = blockIdx.x;                          // b*32 + h
    const float* __restrict__ xsrc = x + (size_t)blk * (32 * 384);

    // ---------------- phase 1: stage x ----------------
    {
        const float4* __restrict__ s4 = (const float4*)xsrc;
#pragma unroll
        for (int k = 0; k < 12; ++k) {
            int f = t + (k << 8);                        // f4 index 0..3071
            int w = f / 96, c = f - w * 96;
            float4 v = s4[f];
            *(float4*)&xs[(w * 97 + c) << 2] = v;
        }
    }
    __syncthreads();

    // ---------------- phase 2: conv2d (y), split-K over waves ----------------
    {
        const int wave = t >> 6, lane = t & 63;
        const int e0 = (lane >> 4) << 2;                 // 0,4,8,12
        const int w0 = (lane & 15) << 1;                 // 0,2,...,30
        float acc[4][2];
#pragma unroll
        for (int e = 0; e < 4; ++e) { acc[e][0] = 0.f; acc[e][1] = 0.f; }
        const float4* __restrict__ w2 = (const float4*)W2d;   // [16][96] f4
        const int d4b = wave * 24;                       // 96 floats per wave
#pragma unroll 4
        for (int i = 0; i < 24; ++i) {
            const int d4 = d4b + i;
            float4 xa = *(const float4*)&xs[(w0 * 97 + d4) << 2];
            float4 xb = *(const float4*)&xs[((w0 + 1) * 97 + d4) << 2];
#pragma unroll
            for (int e = 0; e < 4; ++e) {
                float4 wv = w2[(e0 + e) * 96 + d4];
                acc[e][0] += wv.x * xa.x; acc[e][0] += wv.y * xa.y;
                acc[e][0] += wv.z * xa.z; acc[e][0] += wv.w * xa.w;
                acc[e][1] += wv.x * xb.x; acc[e][1] += wv.y * xb.y;
                acc[e][1] += wv.z * xb.z; acc[e][1] += wv.w * xb.w;
            }
        }
#pragma unroll
        for (int e = 0; e < 4; ++e) {
            red[(wave << 9) + ((e0 + e) << 5) + w0]     = acc[e][0];
            red[(wave << 9) + ((e0 + e) << 5) + w0 + 1] = acc[e][1];
        }
    }
    __syncthreads();
    {
#pragma unroll
        for (int i = t; i < 512; i += 256) {
            ys[i] = red[i] + red[512 + i] + red[1024 + i] + red[1536 + i]
                  + b2d[i >> 5];
        }
    }
    __syncthreads();

    // ---------------- phase 3: conv1d (z) + softmax -> attn ----------------
    {
        const int g = t >> 5, l = t & 31;
        float acc[4] = {0.f, 0.f, 0.f, 0.f};
        if (WBF) {
            const uint4* __restrict__ wp = (const uint4*)Wt + (g << 10);
#pragma unroll
            for (int k = 0; k < 8; ++k) {
                float4 ya = *(const float4*)&ys[(g << 6) + (k << 3)];
                float4 yb = *(const float4*)&ys[(g << 6) + (k << 3) + 4];
#pragma unroll
                for (int j = 0; j < 4; ++j) {
                    uint4 wv = wp[(k << 7) + l + (j << 5)];
                    float c0 = __uint_as_float(wv.x << 16);
                    float c1 = __uint_as_float(wv.x & 0xFFFF0000u);
                    float c2 = __uint_as_float(wv.y << 16);
                    float c3 = __uint_as_float(wv.y & 0xFFFF0000u);
                    float c4 = __uint_as_float(wv.z << 16);
                    float c5 = __uint_as_float(wv.z & 0xFFFF0000u);
                    float c6 = __uint_as_float(wv.w << 16);
                    float c7 = __uint_as_float(wv.w & 0xFFFF0000u);
                    acc[j] += c0 * ya.x; acc[j] += c1 * ya.y;
                    acc[j] += c2 * ya.z; acc[j] += c3 * ya.w;
                    acc[j] += c4 * yb.x; acc[j] += c5 * yb.y;
                    acc[j] += c6 * yb.z; acc[j] += c7 * yb.w;
                }
            }
        } else {
#pragma unroll
            for (int k = 0; k < 8; ++k) {
                float4 ya = *(const float4*)&ys[(g << 6) + (k << 3)];
                float4 yb = *(const float4*)&ys[(g << 6) + (k << 3) + 4];
#pragma unroll
                for (int j = 0; j < 4; ++j) {
                    const float* wr = W1d + (((g << 7) + l + (j << 5)) << 6) + (k << 3);
                    float4 wa = *(const float4*)wr;
                    float4 wb = *(const float4*)(wr + 4);
                    acc[j] += wa.x * ya.x; acc[j] += wa.y * ya.y;
                    acc[j] += wa.z * ya.z; acc[j] += wa.w * ya.w;
                    acc[j] += wb.x * yb.x; acc[j] += wb.y * yb.y;
                    acc[j] += wb.z * yb.z; acc[j] += wb.w * yb.w;
                }
            }
        }
#pragma unroll
        for (int j = 0; j < 4; ++j) acc[j] += b1d[(g << 7) + (j << 5) + l];

        // softmax over v (= lane within 32-lane group), one row per acc[j]
#pragma unroll
        for (int j = 0; j < 4; ++j) {
            float m = acc[j];
#pragma unroll
            for (int s = 16; s >= 1; s >>= 1) m = fmaxf(m, __shfl_xor(m, s, 32));
            float p = __expf(acc[j] - m);
            float ssum = p;
#pragma unroll
            for (int s = 16; s >= 1; s >>= 1) ssum += __shfl_xor(ssum, s, 32);
            zs[(((g << 2) + j) << 5) + l] = __fdividef(p, ssum);
        }
    }
    __syncthreads();

    // ---------------- phase 4: mixing out = attn . x ----------------
    {
        const int ug = t >> 5, l = t & 31;
        float4 acc[4][3];
#pragma unroll
        for (int j = 0; j < 4; ++j)
#pragma unroll
            for (int k = 0; k < 3; ++k) acc[j][k] = make_float4(0.f, 0.f, 0.f, 0.f);

        for (int v = 0; v < 32; ++v) {
            float4 xv[3];
#pragma unroll
            for (int k = 0; k < 3; ++k)
                xv[k] = *(const float4*)&xs[(v * 97 + l + (k << 5)) << 2];
#pragma unroll
            for (int j = 0; j < 4; ++j) {
                float a = zs[((ug + (j << 3)) << 5) + v];
#pragma unroll
                for (int k = 0; k < 3; ++k) {
                    acc[j][k].x += a * xv[k].x;
                    acc[j][k].y += a * xv[k].y;
                    acc[j][k].z += a * xv[k].z;
                    acc[j][k].w += a * xv[k].w;
                }
            }
        }
        float* __restrict__ obase = out + (size_t)blk * (32 * 384);
#pragma unroll
        for (int j = 0; j < 4; ++j) {
            const int u = ug + (j << 3);
#pragma unroll
            for (int k = 0; k < 3; ++k)
                *(float4*)&obase[u * 384 + ((l + (k << 5)) << 2)] = acc[j][k];
        }
    }
}

// ---------------------------------------------------------------------------
extern "C" void kernel_launch(void* const* d_in, const int* in_sizes, int n_in,
                              void* d_out, int out_size, void* d_ws, size_t ws_size,
                              hipStream_t stream) {
    const float* x   = (const float*)d_in[0];
    const float* W2d = (const float*)d_in[1];
    const float* b2d = (const float*)d_in[2];
    const float* W1d = (const float*)d_in[3];
    const float* b1d = (const float*)d_in[4];
    float* out = (float*)d_out;

    const size_t wt_bytes = 8 * 8 * 128 * 8 * sizeof(ushort_t);   // 131072
    if (ws_size >= wt_bytes) {
        ushort_t* Wt = (ushort_t*)d_ws;
        w1d_to_bf16<<<32, 256, 0, stream>>>(W1d, Wt);
        dynamixer_fused<true><<<4096, 256, 0, stream>>>(x, W2d, b2d, W1d, b1d, Wt, out);
    } else {
        dynamixer_fused<false><<<4096, 256, 0, stream>>>(x, W2d, b2d, W1d, b1d, nullptr, out);
    }
}